// Round 8
// baseline (207.636 us; speedup 1.0000x reference)
//
#include <hip/hip_runtime.h>
#include <cstdint>

#define N_ROWS 32768
#define KDIM 1024
#define DDIM 256

typedef __attribute__((ext_vector_type(8))) short bf16x8;
typedef __attribute__((ext_vector_type(4))) float f32x4;

__device__ __forceinline__ unsigned short f2bf(float f) {
  unsigned int u = __float_as_uint(f);
  u += 0x7FFFu + ((u >> 16) & 1u);
  return (unsigned short)(u >> 16);
}
__device__ __forceinline__ float bf2f(unsigned short b) {
  return __uint_as_float((unsigned int)b << 16);
}

// async global->LDS, 16B per lane. LDS dest = wave-uniform base + lane*16.
__device__ __forceinline__ void gload_lds16(const void* g, void* l) {
  __builtin_amdgcn_global_load_lds(
      (const __attribute__((address_space(1))) unsigned int*)(uintptr_t)g,
      (__attribute__((address_space(3))) unsigned int*)(unsigned int)(uintptr_t)l,
      16, 0, 0);
}

// Global layouts (u16 offsets), XOR chunk swizzle baked in (chunk = 8 u16 = 16 B):
// Cn64 [t=c>>6][kb=d>>5][c&63][32]: off = t*16384 + kb*2048 + (c&63)*32 + ((((d&31)>>3)^(c&3))*8) + (d&7)
// CnT  [s=c>>5][d][32]:            off = s*8192 + d*32 + ((((c&31)>>3)^(d&3))*8) + (c&7)
// Mn: Gram matrix M=C^T C in Cn64-style layout with "codes" = b-dims (256).
// Fragment reads use chunk = l4 ^ (l15&3) -> 2-way bank aliasing only (free).

// ---------------- normalize codebook -> Cn64, CnT (bf16, swizzled); also m = sum_k c_hat_k
__global__ __launch_bounds__(256) void k_norm_cb(const float* __restrict__ cb,
                                                 unsigned short* __restrict__ Cn,
                                                 unsigned short* __restrict__ CnT,
                                                 float* __restrict__ m_g) {
  __shared__ float msh[4][256];
  const int wid = threadIdx.x >> 6, lane = threadIdx.x & 63;
  const int k = blockIdx.x * 4 + wid;  // 1024 codes
  float4 v = ((const float4*)(cb + (size_t)k * DDIM))[lane];
  float s = v.x * v.x + v.y * v.y + v.z * v.z + v.w * v.w;
#pragma unroll
  for (int m = 32; m; m >>= 1) s += __shfl_xor(s, m, 64);
  const float rn = 1.0f / sqrtf(s);
  ushort4 p;
  p.x = f2bf(v.x * rn); p.y = f2bf(v.y * rn);
  p.z = f2bf(v.z * rn); p.w = f2bf(v.w * rn);
  const int kb = lane >> 3;
  const int physA = ((lane & 7) >> 1) ^ (k & 3);
  *(ushort4*)(Cn + (size_t)(k >> 6) * 16384 + kb * 2048 + (k & 63) * 32 + physA * 8 + (lane & 1) * 4) = p;
  const int sgl = k >> 5, c31 = k & 31, ch = c31 >> 3, cw = c31 & 7;
  const unsigned short pv[4] = {p.x, p.y, p.z, p.w};
#pragma unroll
  for (int j = 0; j < 4; ++j) {
    const int d = lane * 4 + j;
    CnT[(size_t)sgl * 8192 + d * 32 + ((ch ^ j) * 8) + cw] = pv[j];
    msh[wid][d] = bf2f(pv[j]);  // bf16-rounded (matches MFMA operands)
  }
  __syncthreads();
  const int tid = threadIdx.x;
  if (tid < 256) atomicAdd(&m_g[tid], msh[0][tid] + msh[1][tid] + msh[2][tid] + msh[3][tid]);
}

// ---------------- k_gram: M = C_hat^T C_hat (256x256 bf16) -> Mn (Cn64-style layout).
// 16 blocks x 1024 thr: per iter, ONE gload/thread stages the 16-KB tile; wave wv
// computes 16 a x 16 b with a single MFMA. 4-deep ring, counted vmcnt.
__global__ __launch_bounds__(1024) void k_gram(const unsigned short* __restrict__ CnT,
                                               unsigned short* __restrict__ Mn) {
  __shared__ unsigned short T[4][8192];  // 64 KB ring
  const int tid = threadIdx.x, wv = tid >> 6, lane = tid & 63;
  const int l15 = lane & 15, l4 = lane >> 4;
  const int ab = blockIdx.x;  // a-tile 0..15
  const int xsw = l4 ^ (l15 & 3);
  f32x4 acc = {};
#define STAGE_T(KS, SLOT) \
  gload_lds16(CnT + (size_t)(KS) * 8192 + tid * 8, (char*)T[SLOT] + (size_t)tid * 16)
  STAGE_T(0, 0); STAGE_T(1, 1); STAGE_T(2, 2);  // 3 in flight (1 load/thread each)
  for (int ks = 0; ks < 32; ++ks) {
    if (ks <= 29)      asm volatile("s_waitcnt vmcnt(2)" ::: "memory");
    else if (ks == 30) asm volatile("s_waitcnt vmcnt(1)" ::: "memory");
    else               asm volatile("s_waitcnt vmcnt(0)" ::: "memory");
    __builtin_amdgcn_s_barrier();
    __builtin_amdgcn_sched_barrier(0);
    const unsigned short* B = T[ks & 3];
    bf16x8 a = *(const bf16x8*)&B[(ab * 16 + l15) * 32 + xsw * 8];
    bf16x8 b = *(const bf16x8*)&B[(wv * 16 + l15) * 32 + xsw * 8];
    acc = __builtin_amdgcn_mfma_f32_16x16x32_bf16(a, b, acc, 0, 0, 0);
    __builtin_amdgcn_s_barrier();
    __builtin_amdgcn_sched_barrier(0);
    if (ks <= 28) STAGE_T(ks + 3, (ks + 3) & 3);
  }
#undef STAGE_T
  // write: a_ = ab*16 + l4*4 + reg; b_ = wv*16 + l15
#pragma unroll
  for (int reg = 0; reg < 4; ++reg) {
    const int a_ = ab * 16 + l4 * 4 + reg;
    const int b_ = wv * 16 + l15;
    Mn[(size_t)(b_ >> 6) * 16384 + (a_ >> 5) * 2048 + (b_ & 63) * 32 +
       ((((a_ & 31) >> 3) ^ (b_ & 3)) * 8) + (a_ & 7)] = f2bf(acc[reg]);
  }
}

// ---------------- k_all: one block = 128 rows, 256 blocks (1/CU), 1024 threads.
// R8: 16 waves (4 waves/SIMD) on the SAME work: wave map 4 row-groups x 4 col-groups
// (wave = 32 rows x 16 S-cols / 64 PV-dims). Work, layouts, barriers unchanged from R7;
// only the wave-level parallelism doubles, to hide the dependency-chain stalls that
// counted-vmcnt (R2, R7 nulls) proved are not stage-latency.
// Series denominator: r_hat = K + u + t/2 -> single streaming pass.
__global__ __launch_bounds__(1024, 4) void k_all(const float* __restrict__ x,
                                                 const unsigned short* __restrict__ Cn,
                                                 const unsigned short* __restrict__ CnT,
                                                 const unsigned short* __restrict__ Mn,
                                                 const float* __restrict__ m_g,
                                                 float* __restrict__ colsum_g,
                                                 float* __restrict__ accL,
                                                 int* __restrict__ cnt2,
                                                 float* __restrict__ out) {
  __shared__ unsigned short Cb[4][16384];   // 128 KB ring (32 KB slots); Cb[0..1] = Xs transient
  __shared__ unsigned short Ps[128 * 72];   // 18 KB, stride 72 (16B-aligned, bank-spread)
  __shared__ float csl[1024];
  __shared__ float u_sh[128], t_sh[128], irl[128];
  __shared__ float lse_sh[2];
  __shared__ float sh1[4], sh2[4];
  __shared__ int lastf;

  const int tid = threadIdx.x, wid = tid >> 6, lane = tid & 63;
  const int l15 = lane & 15, l4 = lane >> 4;
  const int wm = wid >> 2, wn = wid & 3;  // 4 row-groups x 4 col-groups
  const int rb = blockIdx.x;              // 256 blocks x 128 rows
  if (tid < 128) t_sh[tid] = 0.f;
  if (tid < 1024) csl[tid] = 0.f;

#define STAGE32(SRC, DST)                                          \
  do {                                                             \
    _Pragma("unroll") for (int i_ = 0; i_ < 2; ++i_) {             \
      const int off_ = i_ * 16384 + tid * 16;                      \
      gload_lds16((const char*)(SRC) + off_, (char*)(DST) + off_); \
    }                                                              \
  } while (0)

  // early stage: M tile0 -> s2, tile1 -> s3 (overlaps norm phase)
  STAGE32(Mn, Cb[2]);
  STAGE32((const char*)Mn + 32768, Cb[3]);

  // norm: one wave per row, 8 passes -> Xs (= Cb[0..1], plain layout); also u = x_hat.m
  unsigned short* Xs = &Cb[0][0];
  const float4 mv = ((const float4*)m_g)[lane];
#pragma unroll
  for (int p8 = 0; p8 < 8; ++p8) {
    const int row = p8 * 16 + wid;
    float4 v = ((const float4*)(x + (size_t)(rb * 128 + row) * DDIM))[lane];
    float s = v.x * v.x + v.y * v.y + v.z * v.z + v.w * v.w;
#pragma unroll
    for (int m = 32; m; m >>= 1) s += __shfl_xor(s, m, 64);
    const float rn = 1.0f / sqrtf(s);
    ushort4 p;
    p.x = f2bf(v.x * rn); p.y = f2bf(v.y * rn);
    p.z = f2bf(v.z * rn); p.w = f2bf(v.w * rn);
    *(ushort4*)&Xs[(lane >> 3) * 4096 + row * 32 + (lane & 7) * 4] = p;
    float ud = bf2f(p.x) * mv.x + bf2f(p.y) * mv.y + bf2f(p.z) * mv.z + bf2f(p.w) * mv.w;
#pragma unroll
    for (int m = 32; m; m >>= 1) ud += __shfl_xor(ud, m, 64);
    if (lane == 0) u_sh[row] = ud;
  }
  __syncthreads();  // Xs visible; M0/M1 landed (full drain)
  // A-fragments -> registers (one-time)
  bf16x8 areg[2][8];
#pragma unroll
  for (int mi = 0; mi < 2; ++mi)
#pragma unroll
    for (int kb = 0; kb < 8; ++kb)
      areg[mi][kb] = *(const bf16x8*)&Xs[kb * 4096 + (wm * 32 + mi * 16 + l15) * 32 + l4 * 8];

  const int xsw = l4 ^ (l15 & 3);

  // ---------------- t = rowsum((X_hat @ M) .* X_hat), 4 tiles of 64 b-dims ----------------
  float tacc[2][4] = {{0.f, 0.f, 0.f, 0.f}, {0.f, 0.f, 0.f, 0.f}};
  auto t_step = [&](const unsigned short* Sm, int bbase) {
    f32x4 Y[2] = {};
#pragma unroll
    for (int kb = 0; kb < 8; ++kb) {
      bf16x8 b0 = *(const bf16x8*)&Sm[kb * 2048 + (wn * 16 + l15) * 32 + xsw * 8];
#pragma unroll
      for (int mi = 0; mi < 2; ++mi)
        Y[mi] = __builtin_amdgcn_mfma_f32_16x16x32_bf16(areg[mi][kb], b0, Y[mi], 0, 0, 0);
    }
    const int b = bbase + wn * 16 + l15;
#pragma unroll
    for (int mi = 0; mi < 2; ++mi)
#pragma unroll
      for (int reg = 0; reg < 4; ++reg) {
        const int row = wm * 32 + mi * 16 + l4 * 4 + reg;
        const float xv = bf2f(Xs[(b >> 5) * 4096 + row * 32 + (b & 31)]);
        tacc[mi][reg] += Y[mi][reg] * xv;
      }
  };
  t_step(Cb[2], 0);                           // M0
  __builtin_amdgcn_s_barrier();
  __builtin_amdgcn_sched_barrier(0);
  STAGE32((const char*)Mn + 65536, Cb[2]);    // M2
  t_step(Cb[3], 64);                          // M1
  asm volatile("s_waitcnt vmcnt(0)" ::: "memory");
  __builtin_amdgcn_s_barrier();
  __builtin_amdgcn_sched_barrier(0);
  STAGE32((const char*)Mn + 98304, Cb[3]);    // M3
  t_step(Cb[2], 128);                         // M2
  asm volatile("s_waitcnt vmcnt(0)" ::: "memory");
  __builtin_amdgcn_s_barrier();
  __builtin_amdgcn_sched_barrier(0);
  STAGE32(Cn, Cb[2]);                         // Cn tile0 (in flight through ir phase)
  t_step(Cb[3], 192);                         // M3
  __builtin_amdgcn_s_barrier();               // Cb[3] readers done (Cn0 stays in flight)
  __builtin_amdgcn_sched_barrier(0);
  STAGE32(CnT, Cb[3]);                        // CnT tile0 (in flight into kt=0)

  // reduce t over l15
#pragma unroll
  for (int mi = 0; mi < 2; ++mi)
#pragma unroll
    for (int reg = 0; reg < 4; ++reg) {
#pragma unroll
      for (int m = 1; m < 16; m <<= 1) tacc[mi][reg] += __shfl_xor(tacc[mi][reg], m, 64);
    }
  if (l15 == 0) {
#pragma unroll
    for (int mi = 0; mi < 2; ++mi)
#pragma unroll
      for (int reg = 0; reg < 4; ++reg)
        atomicAdd(&t_sh[wm * 32 + mi * 16 + l4 * 4 + reg], tacc[mi][reg]);
  }
  asm volatile("s_waitcnt lgkmcnt(0)" ::: "memory");
  __builtin_amdgcn_s_barrier();               // t_sh final (no vm drain!)
  if (tid < 128) {
    const float uu = u_sh[tid], tt = t_sh[tid];
    const float r = (float)KDIM + uu + 0.5f * tt;       // series r
    const float ir = 1.0f / r;
    irl[tid] = ir;
    const float q = (float)KDIM + 2.0f * uu + 2.0f * tt;  // series sum exp(2s)
    float lse = logf((float)(KDIM + 1) + 0.5f * q * ir * ir);
#pragma unroll
    for (int m = 32; m; m >>= 1) lse += __shfl_xor(lse, m, 64);
    if ((tid & 63) == 0) lse_sh[tid >> 6] = lse;
  }
  asm volatile("s_waitcnt lgkmcnt(0)" ::: "memory");
  __builtin_amdgcn_s_barrier();               // irl, lse_sh visible (no vm drain)
  f32x4 ir2[2];
#pragma unroll
  for (int mi = 0; mi < 2; ++mi)
    ir2[mi] = *(const f32x4*)&irl[wm * 32 + mi * 16 + l4 * 4];
  asm volatile("s_waitcnt vmcnt(2)" ::: "memory");  // Cn0 landed; CnT0 in flight
  __builtin_amdgcn_s_barrier();
  __builtin_amdgcn_sched_barrier(0);

  // ---------------- single streaming pass: S, exp, Ps, colsum(ir), PV ----------------
  f32x4 O[2][4] = {};
  const int psw_r = l15 >> 1;
  for (int kt = 0; kt < 16; ++kt) {
    const int cslot = (kt & 1) ? 0 : 2;   // Cn(kt)
    const int tslot = cslot | 1;          // CnT(kt)
    const int nslot = (kt & 1) ? 2 : 0;   // target pair for kt+1
    if (kt < 15) {
      STAGE32((const char*)Cn + (size_t)(kt + 1) * 32768, Cb[nslot]);
      STAGE32((const char*)CnT + (size_t)(kt + 1) * 32768, Cb[nslot + 1]);
    }
    // S: wave's 16 cols (wn*16..)
    f32x4 S[2] = {};
#pragma unroll
    for (int kb = 0; kb < 8; ++kb) {
      bf16x8 b = *(const bf16x8*)&Cb[cslot][kb * 2048 + (wn * 16 + l15) * 32 + xsw * 8];
#pragma unroll
      for (int mi = 0; mi < 2; ++mi)
        S[mi] = __builtin_amdgcn_mfma_f32_16x16x32_bf16(areg[mi][kb], b, S[mi], 0, 0, 0);
    }
    // epilogue: exp -> Ps (stride 72, swizzled); colsum partials with known ir
    const int chl = wn * 2 + (l15 >> 3);
    float cs = 0.f;
#pragma unroll
    for (int mi = 0; mi < 2; ++mi)
#pragma unroll
      for (int reg = 0; reg < 4; ++reg) {
        const int row = wm * 32 + mi * 16 + l4 * 4 + reg;
        const int pswz = (l4 * 2 + (reg >> 1)) & 7;  // ((row&15)>>1)
        const float e = __expf(S[mi][reg]);
        Ps[row * 72 + ((chl ^ pswz) * 8) + (l15 & 7)] = f2bf(e);
        cs += e * ir2[mi][reg];
      }
    cs += __shfl_xor(cs, 16, 64);
    cs += __shfl_xor(cs, 32, 64);
    if (lane < 16) atomicAdd(&csl[kt * 64 + wn * 16 + l15], cs);
    // sync#1: Ps visible + CnT[kt] landed; next-tile stages stay in flight
    if (kt < 15) asm volatile("s_waitcnt vmcnt(4) lgkmcnt(0)" ::: "memory");
    else         asm volatile("s_waitcnt vmcnt(0) lgkmcnt(0)" ::: "memory");
    __builtin_amdgcn_s_barrier();
    __builtin_amdgcn_sched_barrier(0);
    // PV: O += Ps @ CnT[kt]; wave's 64 dims (wn*64..)
#pragma unroll
    for (int kb2 = 0; kb2 < 2; ++kb2) {
      bf16x8 a2[2], b2[4];
#pragma unroll
      for (int mi = 0; mi < 2; ++mi) {
        const int row = wm * 32 + mi * 16 + l15;
        a2[mi] = *(const bf16x8*)&Ps[row * 72 + (((kb2 * 4 + l4) ^ psw_r) * 8)];
      }
#pragma unroll
      for (int ni = 0; ni < 4; ++ni) {
        const int d = wn * 64 + ni * 16 + l15;
        b2[ni] = *(const bf16x8*)&Cb[tslot][kb2 * 8192 + d * 32 + xsw * 8];
      }
#pragma unroll
      for (int mi = 0; mi < 2; ++mi)
#pragma unroll
        for (int ni = 0; ni < 4; ++ni)
          O[mi][ni] = __builtin_amdgcn_mfma_f32_16x16x32_bf16(a2[mi], b2[ni], O[mi][ni], 0, 0, 0);
    }
    // sync#2: Cn[kt+1] landed; CnT[kt+1] stays in flight
    if (kt < 15) asm volatile("s_waitcnt vmcnt(2)" ::: "memory");
    else         asm volatile("s_waitcnt vmcnt(0)" ::: "memory");
    __builtin_amdgcn_s_barrier();
    __builtin_amdgcn_sched_barrier(0);
  }

  // out = O * ir
#pragma unroll
  for (int mi = 0; mi < 2; ++mi)
#pragma unroll
    for (int reg = 0; reg < 4; ++reg) {
      const int row = wm * 32 + mi * 16 + l4 * 4 + reg;
      const float irv = ir2[mi][reg];
#pragma unroll
      for (int ni = 0; ni < 4; ++ni) {
        const int d = wn * 64 + ni * 16 + l15;
        out[(size_t)(rb * 128 + row) * DDIM + d] = O[mi][ni][reg] * irv;
      }
    }
  // colsum partials -> global atomics; lse -> accL
  if (tid < 1024) atomicAdd(&colsum_g[tid], csl[tid]);
  if (tid == 0) atomicAdd(accL, lse_sh[0] + lse_sh[1]);

  // ---- last block computes the loss (ticket via cnt2; scheduling-safe)
  if (tid == 0) {
    __threadfence();
    const int old = __hip_atomic_fetch_add(cnt2, 1, __ATOMIC_ACQ_REL, __HIP_MEMORY_SCOPE_AGENT);
    lastf = (old == 255);
  }
  __syncthreads();
  if (lastf) {
    if (tid < 256) {
      float s = 0.f, q = 0.f;
#pragma unroll
      for (int j = 0; j < 4; ++j) {
        const float c = __hip_atomic_load(&colsum_g[tid + j * 256], __ATOMIC_RELAXED, __HIP_MEMORY_SCOPE_AGENT);
        s += c; q += c * c;
      }
#pragma unroll
      for (int m = 1; m < 64; m <<= 1) {
        s += __shfl_xor(s, m, 64);
        q += __shfl_xor(q, m, 64);
      }
      if (lane == 0) { sh1[tid >> 6] = s; sh2[tid >> 6] = q; }
    }
    __syncthreads();
    if (tid == 0) {
      const double S = (double)sh1[0] + sh1[1] + sh1[2] + sh1[3];  // sum of all distances (~N)
      const double Q = (double)sh2[0] + sh2[1] + sh2[2] + sh2[3];  // ||colsum||^2
      const double L = __hip_atomic_load(accL, __ATOMIC_RELAXED, __HIP_MEMORY_SCOPE_AGENT);
      const double entropy = (S * L - Q) / (double)N_ROWS;
      const double l1 = S / ((double)N_ROWS * (double)KDIM);
      out[(size_t)N_ROWS * DDIM] = (float)(1000.0 * l1 + 5e-5 * entropy);
    }
  }
#undef STAGE32
}

extern "C" void kernel_launch(void* const* d_in, const int* in_sizes, int n_in,
                              void* d_out, int out_size, void* d_ws, size_t ws_size,
                              hipStream_t stream) {
  const float* x = (const float*)d_in[0];   // [8,4096,256] fp32
  const float* cb = (const float*)d_in[1];  // [1024,256] fp32
  float* out = (float*)d_out;               // recon [8388608] + loss [1]
  char* ws = (char*)d_ws;

  unsigned short* Cn  = (unsigned short*)(ws + 0);         // 524288 B (Cn64 swizzled)
  unsigned short* CnT = (unsigned short*)(ws + 524288);    // 524288 B (CnT swizzled)
  unsigned short* Mn  = (unsigned short*)(ws + 1048576);   // 131072 B (Gram, Cn64-style)
  float* colsum_g     = (float*)(ws + 1179648);            // 4096 B
  float* m_g          = (float*)(ws + 1183744);            // 1024 B (16B-aligned)
  float* accL         = (float*)(ws + 1184768);            // 4 B
  int* cnt2           = (int*)(ws + 1184772);              // 4 B (loss ticket)

  hipMemsetAsync(ws + 1179648, 0, 5128, stream);
  k_norm_cb<<<256, 256, 0, stream>>>(cb, Cn, CnT, m_g);
  k_gram<<<16, 1024, 0, stream>>>(CnT, Mn);
  k_all<<<256, 1024, 0, stream>>>(x, Cn, CnT, Mn, m_g, colsum_g, accL, cnt2, out);
}